// Round 3
// baseline (269.120 us; speedup 1.0000x reference)
//
#include <hip/hip_runtime.h>

typedef unsigned int u32;
typedef unsigned short u16;
typedef short s16x8 __attribute__((ext_vector_type(8)));
typedef float f32x4 __attribute__((ext_vector_type(4)));

#define BETA_MIN 0.1f
#define BETA_MAX 20.0f

#define MFMA16(a, b, c) __builtin_amdgcn_mfma_f32_16x16x32_bf16(a, b, c, 0, 0, 0)

__device__ __forceinline__ u16 f2bf(float f) {
    u32 u = __float_as_uint(f);
    u32 r = u + 0x7FFFu + ((u >> 16) & 1u);   // RNE on bf16 boundary
    return (u16)(r >> 16);
}
__device__ __forceinline__ float bf2f(u16 h) {
    return __uint_as_float(((u32)h) << 16);
}
__device__ __forceinline__ f32x4 zero4() {
    f32x4 z = {0.f, 0.f, 0.f, 0.f};
    return z;
}

// async global->LDS 16B; lds dest must be wave-uniform (HW adds lane*16)
__device__ __forceinline__ void cp16(const u16* g, u16* l) {
    __builtin_amdgcn_global_load_lds(
        (const __attribute__((address_space(1))) u32*)g,
        (__attribute__((address_space(3))) u32*)l, 16, 0, 0);
}

// DPP cross-lane within 16-lane rows (VALU latency, off the LDS pipe)
template <int CTRL>
__device__ __forceinline__ float dppf(float x) {
    return __int_as_float(__builtin_amdgcn_update_dpp(
        0, __float_as_int(x), CTRL, 0xF, 0xF, false));
}
__device__ __forceinline__ float rowmax16(float x) {
    x = fmaxf(x, dppf<0xB1>(x));    // quad_perm xor1
    x = fmaxf(x, dppf<0x4E>(x));    // quad_perm xor2
    x = fmaxf(x, dppf<0x124>(x));   // row_ror:4
    x = fmaxf(x, dppf<0x128>(x));   // row_ror:8
    return x;
}
__device__ __forceinline__ float rowsum16(float x) {
    x += dppf<0xB1>(x);
    x += dppf<0x4E>(x);
    x += dppf<0x124>(x);
    x += dppf<0x128>(x);
    return x;
}

// ---------------------------------------------------------------- prep kernels

// rowc[n] = {a = mean*iv, b = -0.5*mean^2*iv, iv, 0}
__global__ void rows_kernel(const float* __restrict__ t, float* __restrict__ rowc, int N) {
    int n = blockIdx.x * blockDim.x + threadIdx.x;
    if (n >= N) return;
    float tv   = t[n];
    float lm   = -0.25f * tv * tv * (BETA_MAX - BETA_MIN) - 0.5f * tv * BETA_MIN;
    float mean = __expf(lm);
    float e2   = __expf(2.0f * lm);
    float s2   = fmaxf(1.0f - e2, 1e-12f);
    float iv   = 1.0f / s2;
    rowc[n * 4 + 0] = mean * iv;
    rowc[n * 4 + 1] = -0.5f * mean * mean * iv;
    rowc[n * 4 + 2] = iv;
    rowc[n * 4 + 3] = 0.f;
}

// fp32 -> (hi bf16, lo bf16 residual), float4-vectorized
__global__ void conv_hilo(const float* __restrict__ src, u16* __restrict__ hi,
                          u16* __restrict__ lo, int total4) {
    int idx = blockIdx.x * blockDim.x + threadIdx.x;
    if (idx >= total4) return;
    float4 v = ((const float4*)src)[idx];
    float f[4] = {v.x, v.y, v.z, v.w};
    u16 h[4], l[4];
#pragma unroll
    for (int j = 0; j < 4; ++j) {
        h[j] = f2bf(f[j]);
        l[j] = f2bf(f[j] - bf2f(h[j]));
    }
    ((uint2*)hi)[idx] = make_uint2((u32)h[0] | ((u32)h[1] << 16), (u32)h[2] | ((u32)h[3] << 16));
    ((uint2*)lo)[idx] = make_uint2((u32)l[0] | ((u32)l[1] << 16), (u32)l[2] | ((u32)l[3] << 16));
}

// Vt[d][m] = bf16(train[m][d]); y2[m] = ||y_m||^2. One wave per row m.
__global__ void vt_y2_kernel(const float* __restrict__ train, u16* __restrict__ Vt,
                             float* __restrict__ y2, int M) {
    int wave = threadIdx.x >> 6, lane = threadIdx.x & 63;
    int m = blockIdx.x * 4 + wave;
    const float* row = train + (size_t)m * 128;
    float2 v = *(const float2*)(row + lane * 2);
    Vt[(size_t)(lane * 2 + 0) * M + m] = f2bf(v.x);
    Vt[(size_t)(lane * 2 + 1) * M + m] = f2bf(v.y);
    float s = v.x * v.x + v.y * v.y;
#pragma unroll
    for (int d = 1; d < 64; d <<= 1) s += __shfl_xor(s, d);
    if (lane == 0) y2[m] = s;
}

// ---------------------------------------------------------------- flash kernel
// grid = (N/128, split); block = 256 (4 waves, 32 q-rows/wave); K-tile = 32.
// S = a*(Qh*Kh + Ql*Kh + Qh*Kl) + b*y2   (bf16x3)
// K hi/lo: LDS via global_load_lds, XOR-swizzled chunks (chunk' = chunk ^ (row&15)).
// V fragments + y2: straight from global (L1/L2), no LDS.
// sP: per-wave C-layout -> A-layout round trip.
#define SKF(buf, h, kb) \
    (*(const s16x8*)((buf) + ((((h) * 16 + l15) * 16 + ((((kb) * 4) + quad) ^ l15)) * 8)))

__global__ __launch_bounds__(256, 2)
void flash_kernel(const u16* __restrict__ Khi, const u16* __restrict__ Klo,
                  const u16* __restrict__ Vt,  const u16* __restrict__ Qhi,
                  const u16* __restrict__ Qlo, const float* __restrict__ rowc,
                  const float* __restrict__ y2, float* __restrict__ partO,
                  float* __restrict__ partML, int N, int M, int mchunk) {
    __shared__ __align__(16) u16 sKhi[32 * 128];
    __shared__ __align__(16) u16 sKlo[32 * 128];
    __shared__ __align__(16) u16 sP[4][2][16][40];

    const int tid  = threadIdx.x;
    const int wave = tid >> 6, lane = tid & 63;
    const int l15  = lane & 15, quad = lane >> 4;
    const int qb = blockIdx.x, chunk = blockIdx.y;
    const int q0 = qb * 128 + wave * 32;
    const int m_begin = chunk * mchunk;

    // Q fragments (A-layout: A[m=l15][k=quad*8+j]), 2 sub-tiles of 16 rows
    s16x8 qh[2][4], ql[2][4];
#pragma unroll
    for (int i = 0; i < 2; ++i) {
        int row = q0 + i * 16 + l15;
        const u16* ph = Qhi + (size_t)row * 128;
        const u16* pl = Qlo + (size_t)row * 128;
#pragma unroll
        for (int kb = 0; kb < 4; ++kb) {
            qh[i][kb] = *(const s16x8*)(ph + kb * 32 + quad * 8);
            ql[i][kb] = *(const s16x8*)(pl + kb * 32 + quad * 8);
        }
    }
    float av[2][4], bv[2][4];
#pragma unroll
    for (int i = 0; i < 2; ++i)
#pragma unroll
        for (int k = 0; k < 4; ++k) {
            int r = q0 + i * 16 + quad * 4 + k;
            av[i][k] = rowc[r * 4 + 0];
            bv[i][k] = rowc[r * 4 + 1];
        }

    f32x4 O[2][8];
#pragma unroll
    for (int i = 0; i < 2; ++i)
#pragma unroll
        for (int db = 0; db < 8; ++db) O[i][db] = zero4();
    float m_run[2][4], l_run[2][4];
#pragma unroll
    for (int i = 0; i < 2; ++i)
#pragma unroll
        for (int k = 0; k < 4; ++k) { m_run[i][k] = -INFINITY; l_run[i][k] = 0.f; }

    const int cbase = wave * 64 + lane;

    for (int mt = 0; mt < mchunk; mt += 32) {
        const int m0 = m_begin + mt;
        __syncthreads();   // previous tile fully consumed; LDS reusable
        // async stage K hi/lo: 512 chunks each, 16B, XOR-swizzled
#pragma unroll
        for (int r = 0; r < 2; ++r) {
            int c = r * 256 + cbase;
            int row = c >> 4;
            int g = (c & 15) ^ (row & 15);
            cp16(Khi + (size_t)(m0 + row) * 128 + g * 8, &sKhi[(r * 256 + wave * 64) * 8]);
            cp16(Klo + (size_t)(m0 + row) * 128 + g * 8, &sKlo[(r * 256 + wave * 64) * 8]);
        }
        // V fragments + y2 from global; in flight during staging drain
        s16x8 vb[8];
#pragma unroll
        for (int db = 0; db < 8; ++db)
            vb[db] = *(const s16x8*)(Vt + (size_t)(db * 16 + l15) * M + m0 + quad * 8);
        float y2v0 = y2[m0 + l15];
        float y2v1 = y2[m0 + 16 + l15];
        __syncthreads();   // drains vmcnt (global_load_lds) before reads

        // S GEMM: bf16x3, swizzled fragment reads
        f32x4 S[2][2];
#pragma unroll
        for (int i = 0; i < 2; ++i) { S[i][0] = zero4(); S[i][1] = zero4(); }
#pragma unroll
        for (int kb = 0; kb < 4; ++kb) {
            s16x8 bh0 = SKF(sKhi, 0, kb);
            s16x8 bh1 = SKF(sKhi, 1, kb);
            s16x8 bl0 = SKF(sKlo, 0, kb);
            s16x8 bl1 = SKF(sKlo, 1, kb);
#pragma unroll
            for (int i = 0; i < 2; ++i) {
                S[i][0] = MFMA16(qh[i][kb], bh0, S[i][0]);
                S[i][0] = MFMA16(ql[i][kb], bh0, S[i][0]);
                S[i][0] = MFMA16(qh[i][kb], bl0, S[i][0]);
                S[i][1] = MFMA16(qh[i][kb], bh1, S[i][1]);
                S[i][1] = MFMA16(ql[i][kb], bh1, S[i][1]);
                S[i][1] = MFMA16(qh[i][kb], bl1, S[i][1]);
            }
        }

        // online softmax; alpha-mult of O deferred behind a wave-uniform vote
        float alph[2][4];
        int upd = 0;
#pragma unroll
        for (int i = 0; i < 2; ++i) {
#pragma unroll
            for (int k = 0; k < 4; ++k) {
                float s0 = av[i][k] * S[i][0][k] + bv[i][k] * y2v0;
                float s1 = av[i][k] * S[i][1][k] + bv[i][k] * y2v1;
                float rm = rowmax16(fmaxf(s0, s1));
                float mnew  = fmaxf(m_run[i][k], rm);
                float a_    = __expf(m_run[i][k] - mnew);   // ==1 when no update
                float p0 = __expf(s0 - mnew);
                float p1 = __expf(s1 - mnew);
                l_run[i][k] = l_run[i][k] * a_ + (p0 + p1);
                m_run[i][k] = mnew;
                alph[i][k]  = a_;
                upd |= (a_ < 1.0f);
                sP[wave][i][quad * 4 + k][l15]      = f2bf(p0);
                sP[wave][i][quad * 4 + k][16 + l15] = f2bf(p1);
            }
        }
        if (__any(upd)) {
#pragma unroll
            for (int i = 0; i < 2; ++i)
#pragma unroll
                for (int db = 0; db < 8; ++db)
#pragma unroll
                    for (int k = 0; k < 4; ++k) O[i][db][k] *= alph[i][k];
        }
        // same-wave sP write->read ordering
        asm volatile("s_waitcnt lgkmcnt(0)" ::: "memory");

        s16x8 pa0 = *(const s16x8*)&sP[wave][0][l15][quad * 8];
        s16x8 pa1 = *(const s16x8*)&sP[wave][1][l15][quad * 8];
#pragma unroll
        for (int db = 0; db < 8; ++db) {
            O[0][db] = MFMA16(pa0, vb[db], O[0][db]);
            O[1][db] = MFMA16(pa1, vb[db], O[1][db]);
        }
    }

    // epilogue: unnormalized O + (m, l) partials
#pragma unroll
    for (int i = 0; i < 2; ++i) {
#pragma unroll
        for (int db = 0; db < 8; ++db) {
#pragma unroll
            for (int k = 0; k < 4; ++k) {
                int row = q0 + i * 16 + quad * 4 + k;
                partO[((size_t)chunk * N + row) * 128 + db * 16 + l15] = O[i][db][k];
            }
        }
#pragma unroll
        for (int k = 0; k < 4; ++k) {
            float lsum = rowsum16(l_run[i][k]);
            if (l15 == 0) {
                int row = q0 + i * 16 + quad * 4 + k;
                partML[((size_t)chunk * N + row) * 2 + 0] = m_run[i][k];
                partML[((size_t)chunk * N + row) * 2 + 1] = lsum;
            }
        }
    }
}

// ---------------------------------------------------------------- combine
__global__ void combine_kernel(const float* __restrict__ partO, const float* __restrict__ partML,
                               const float* __restrict__ x, const float* __restrict__ rowc,
                               float* __restrict__ out, int N, int split) {
    int n = blockIdx.x, d = threadIdx.x;
    float Mx = -INFINITY;
    for (int c = 0; c < split; ++c)
        Mx = fmaxf(Mx, partML[((size_t)c * N + n) * 2]);
    float L = 0.f, acc = 0.f;
    for (int c = 0; c < split; ++c) {
        float w = __expf(partML[((size_t)c * N + n) * 2] - Mx);
        L   += w * partML[((size_t)c * N + n) * 2 + 1];
        acc += w * partO[((size_t)c * N + n) * 128 + d];
    }
    float evals = acc / L;
    if (evals != evals) evals = 0.f;   // reference's isnan guard
    float iv = rowc[n * 4 + 2];
    out[(size_t)n * 128 + d] = (evals - x[(size_t)n * 128 + d]) * iv;
}

// ---------------------------------------------------------------- launch
extern "C" void kernel_launch(void* const* d_in, const int* in_sizes, int n_in,
                              void* d_out, int out_size, void* d_ws, size_t ws_size,
                              hipStream_t stream) {
    const float* x     = (const float*)d_in[0];
    const float* t     = (const float*)d_in[1];
    const float* train = (const float*)d_in[2];
    float* out = (float*)d_out;

    const int N = in_sizes[1];            // 4096
    const int D = 128;
    const int M = in_sizes[2] / D;        // 16384

    char* ws = (char*)d_ws;
    size_t off = 0;
    auto alloc = [&](size_t bytes) -> void* {
        void* p = ws + off;
        off = (off + bytes + 255) & ~(size_t)255;
        return p;
    };
    u16* Khi   = (u16*)alloc((size_t)M * D * 2);
    u16* Klo   = (u16*)alloc((size_t)M * D * 2);
    u16* Vt    = (u16*)alloc((size_t)M * D * 2);
    u16* Qhi   = (u16*)alloc((size_t)N * D * 2);
    u16* Qlo   = (u16*)alloc((size_t)N * D * 2);
    float* rowc = (float*)alloc((size_t)N * 16);
    float* y2   = (float*)alloc((size_t)M * 4);
    size_t base = off;
    size_t per  = (size_t)N * D * 4 + (size_t)N * 8 + 512;   // partO + partML per chunk
    int split = 32;
    while (split > 1 && base + per * split > ws_size) split >>= 1;
    float* partO  = (float*)alloc((size_t)split * N * D * 4);
    float* partML = (float*)alloc((size_t)split * N * 8);

    rows_kernel<<<(N + 255) / 256, 256, 0, stream>>>(t, rowc, N);
    conv_hilo<<<(N * D / 4 + 255) / 256, 256, 0, stream>>>(x, Qhi, Qlo, N * D / 4);
    conv_hilo<<<(M * D / 4 + 255) / 256, 256, 0, stream>>>(train, Khi, Klo, M * D / 4);
    vt_y2_kernel<<<M / 4, 256, 0, stream>>>(train, Vt, y2, M);

    int mchunk = M / split;
    dim3 grid(N / 128, split);
    flash_kernel<<<grid, 256, 0, stream>>>(Khi, Klo, Vt, Qhi, Qlo, rowc, y2,
                                           partO, partML, N, M, mchunk);
    combine_kernel<<<N, 128, 0, stream>>>(partO, partML, x, rowc, out, N, split);
}

// Round 4
// 239.262 us; speedup vs baseline: 1.1248x; 1.1248x over previous
//
#include <hip/hip_runtime.h>

typedef unsigned int u32;
typedef unsigned short u16;
typedef short s16x8 __attribute__((ext_vector_type(8)));
typedef float f32x4 __attribute__((ext_vector_type(4)));

#define BETA_MIN 0.1f
#define BETA_MAX 20.0f

#define MFMA16(a, b, c) __builtin_amdgcn_mfma_f32_16x16x32_bf16(a, b, c, 0, 0, 0)

__device__ __forceinline__ u16 f2bf(float f) {
    u32 u = __float_as_uint(f);
    u32 r = u + 0x7FFFu + ((u >> 16) & 1u);   // RNE on bf16 boundary
    return (u16)(r >> 16);
}
__device__ __forceinline__ float bf2f(u16 h) {
    return __uint_as_float(((u32)h) << 16);
}
__device__ __forceinline__ f32x4 zero4() {
    f32x4 z = {0.f, 0.f, 0.f, 0.f};
    return z;
}

// async global->LDS 16B; lds dest wave-uniform (HW adds lane*16)
__device__ __forceinline__ void cp16(const u16* g, u16* l) {
    __builtin_amdgcn_global_load_lds(
        (const __attribute__((address_space(1))) u32*)g,
        (__attribute__((address_space(3))) u32*)l, 16, 0, 0);
}

// DPP cross-lane within 16-lane rows (VALU latency, off the LDS pipe)
template <int CTRL>
__device__ __forceinline__ float dppf(float x) {
    return __int_as_float(__builtin_amdgcn_update_dpp(
        0, __float_as_int(x), CTRL, 0xF, 0xF, false));
}
__device__ __forceinline__ float rowmax16(float x) {
    x = fmaxf(x, dppf<0xB1>(x));    // quad_perm xor1
    x = fmaxf(x, dppf<0x4E>(x));    // quad_perm xor2
    x = fmaxf(x, dppf<0x124>(x));   // row_ror:4
    x = fmaxf(x, dppf<0x128>(x));   // row_ror:8
    return x;
}
__device__ __forceinline__ float rowsum16(float x) {
    x += dppf<0xB1>(x);
    x += dppf<0x4E>(x);
    x += dppf<0x124>(x);
    x += dppf<0x128>(x);
    return x;
}

// ---------------------------------------------------------------- prep kernels
// P1: conv_hilo(x) for all blocks + rows_kernel folded into low blocks.
__global__ void prep_x_kernel(const float* __restrict__ x, const float* __restrict__ t,
                              u16* __restrict__ Qhi, u16* __restrict__ Qlo,
                              float* __restrict__ rowc, int N) {
    int idx = blockIdx.x * 256 + threadIdx.x;
    int total4 = N * 32;                       // N*128/4 float4 chunks
    if (idx < total4) {
        float4 v = ((const float4*)x)[idx];
        float f[4] = {v.x, v.y, v.z, v.w};
        u16 h[4], l[4];
#pragma unroll
        for (int j = 0; j < 4; ++j) {
            h[j] = f2bf(f[j]);
            l[j] = f2bf(f[j] - bf2f(h[j]));
        }
        ((uint2*)Qhi)[idx] = make_uint2((u32)h[0] | ((u32)h[1] << 16), (u32)h[2] | ((u32)h[3] << 16));
        ((uint2*)Qlo)[idx] = make_uint2((u32)l[0] | ((u32)l[1] << 16), (u32)l[2] | ((u32)l[3] << 16));
    }
    if (idx < N) {
        float tv   = t[idx];
        float lm   = -0.25f * tv * tv * (BETA_MAX - BETA_MIN) - 0.5f * tv * BETA_MIN;
        float mean = __expf(lm);
        float e2   = __expf(2.0f * lm);
        float s2   = fmaxf(1.0f - e2, 1e-12f);
        float iv   = 1.0f / s2;
        rowc[idx * 4 + 0] = mean * iv;
        rowc[idx * 4 + 1] = -0.5f * mean * mean * iv;
        rowc[idx * 4 + 2] = iv;
        rowc[idx * 4 + 3] = 0.f;
    }
}

// P2: one wave per train row m: Khi/Klo rows (coalesced u32), Vt column scatter, y2.
// Single pass over the 16 MB train array (was two kernels = two passes).
__global__ void prep_train_kernel(const float* __restrict__ train, u16* __restrict__ Khi,
                                  u16* __restrict__ Klo, u16* __restrict__ Vt,
                                  float* __restrict__ y2, int M) {
    int wave = threadIdx.x >> 6, lane = threadIdx.x & 63;
    int m = blockIdx.x * 4 + wave;
    const float* row = train + (size_t)m * 128;
    float2 v = *(const float2*)(row + lane * 2);
    u16 h0 = f2bf(v.x), l0 = f2bf(v.x - bf2f(h0));
    u16 h1 = f2bf(v.y), l1 = f2bf(v.y - bf2f(h1));
    ((u32*)Khi)[(size_t)m * 64 + lane] = (u32)h0 | ((u32)h1 << 16);
    ((u32*)Klo)[(size_t)m * 64 + lane] = (u32)l0 | ((u32)l1 << 16);
    Vt[(size_t)(lane * 2 + 0) * M + m] = h0;
    Vt[(size_t)(lane * 2 + 1) * M + m] = h1;
    float s = v.x * v.x + v.y * v.y;
#pragma unroll
    for (int d = 1; d < 64; d <<= 1) s += __shfl_xor(s, d);
    if (lane == 0) y2[m] = s;
}

// ---------------------------------------------------------------- flash kernel
// grid = (N/128, split); block = 256 (4 waves, 32 q-rows/wave); K-tile = 32.
// S = a*(Qh*Kh + Ql*Kh + Qh*Kl) + b*y2   (bf16x3)
// K hi/lo: DOUBLE-BUFFERED LDS via global_load_lds, XOR-swizzled chunks.
//   Pipeline: [issue stage(i+1) | load V(i) | compute(i) | waitcnt+barrier].
//   One barrier per iteration; staging drain lands AFTER compute, not before.
// V fragments + y2: from global (L1-resident slice), issued early in compute.
__device__ __forceinline__ s16x8 skf(const u16* buf, int h, int kb, int l15, int quad) {
    return *(const s16x8*)(buf + (((h * 16 + l15) * 16 + (((kb * 4) + quad) ^ l15)) * 8));
}

__global__ __launch_bounds__(256, 2)
void flash_kernel(const u16* __restrict__ Khi, const u16* __restrict__ Klo,
                  const u16* __restrict__ Vt,  const u16* __restrict__ Qhi,
                  const u16* __restrict__ Qlo, const float* __restrict__ rowc,
                  const float* __restrict__ y2, float* __restrict__ partO,
                  float* __restrict__ partML, int N, int M, int mchunk) {
    __shared__ __align__(16) u16 sKhi[2][32 * 128];
    __shared__ __align__(16) u16 sKlo[2][32 * 128];
    __shared__ __align__(16) u16 sP[4][2][16][40];

    const int tid  = threadIdx.x;
    const int wave = tid >> 6, lane = tid & 63;
    const int l15  = lane & 15, quad = lane >> 4;
    const int qb = blockIdx.x, chunk = blockIdx.y;
    const int q0 = qb * 128 + wave * 32;
    const int m_begin = chunk * mchunk;
    const int cbase = wave * 64 + lane;

    // Q fragments (A-layout: A[m=l15][k=quad*8+j]), 2 sub-tiles of 16 rows
    s16x8 qh[2][4], ql[2][4];
#pragma unroll
    for (int i = 0; i < 2; ++i) {
        int row = q0 + i * 16 + l15;
        const u16* ph = Qhi + (size_t)row * 128;
        const u16* pl = Qlo + (size_t)row * 128;
#pragma unroll
        for (int kb = 0; kb < 4; ++kb) {
            qh[i][kb] = *(const s16x8*)(ph + kb * 32 + quad * 8);
            ql[i][kb] = *(const s16x8*)(pl + kb * 32 + quad * 8);
        }
    }
    float av[2][4], bv[2][4];
#pragma unroll
    for (int i = 0; i < 2; ++i)
#pragma unroll
        for (int k = 0; k < 4; ++k) {
            int r = q0 + i * 16 + quad * 4 + k;
            av[i][k] = rowc[r * 4 + 0];
            bv[i][k] = rowc[r * 4 + 1];
        }

    f32x4 O[2][8];
#pragma unroll
    for (int i = 0; i < 2; ++i)
#pragma unroll
        for (int db = 0; db < 8; ++db) O[i][db] = zero4();
    float m_run[2][4], l_run[2][4];
#pragma unroll
    for (int i = 0; i < 2; ++i)
#pragma unroll
        for (int k = 0; k < 4; ++k) { m_run[i][k] = -INFINITY; l_run[i][k] = 0.f; }

    // stage K-tile m0 into dbuf half b: 512 swizzled 16B chunks each for hi/lo
    auto stage = [&](int m0, int b) {
#pragma unroll
        for (int r = 0; r < 2; ++r) {
            int c = r * 256 + cbase;
            int row = c >> 4;
            int g = (c & 15) ^ (row & 15);
            cp16(Khi + (size_t)(m0 + row) * 128 + g * 8, &sKhi[b][(r * 256 + wave * 64) * 8]);
            cp16(Klo + (size_t)(m0 + row) * 128 + g * 8, &sKlo[b][(r * 256 + wave * 64) * 8]);
        }
    };

    // prologue: tile 0 -> buf 0
    stage(m_begin, 0);
    asm volatile("s_waitcnt vmcnt(0)" ::: "memory");
    __syncthreads();

    const int iters = mchunk / 32;
    for (int it = 0; it < iters; ++it) {
        const int m0 = m_begin + it * 32;
        const u16* bKhi = sKhi[it & 1];
        const u16* bKlo = sKlo[it & 1];

        // issue next tile's staging into the other half (overlaps this compute)
        if (it + 1 < iters) stage(m0 + 32, (it + 1) & 1);

        // V fragments + y2 for CURRENT tile (global; consumed ~600cyc later in PV)
        s16x8 vb[8];
#pragma unroll
        for (int db = 0; db < 8; ++db)
            vb[db] = *(const s16x8*)(Vt + (size_t)(db * 16 + l15) * M + m0 + quad * 8);
        float y2v0 = y2[m0 + l15];
        float y2v1 = y2[m0 + 16 + l15];

        // S GEMM: bf16x3, swizzled fragment reads from current buffer
        f32x4 S[2][2];
#pragma unroll
        for (int i = 0; i < 2; ++i) { S[i][0] = zero4(); S[i][1] = zero4(); }
#pragma unroll
        for (int kb = 0; kb < 4; ++kb) {
            s16x8 bh0 = skf(bKhi, 0, kb, l15, quad);
            s16x8 bh1 = skf(bKhi, 1, kb, l15, quad);
            s16x8 bl0 = skf(bKlo, 0, kb, l15, quad);
            s16x8 bl1 = skf(bKlo, 1, kb, l15, quad);
#pragma unroll
            for (int i = 0; i < 2; ++i) {
                S[i][0] = MFMA16(qh[i][kb], bh0, S[i][0]);
                S[i][0] = MFMA16(ql[i][kb], bh0, S[i][0]);
                S[i][0] = MFMA16(qh[i][kb], bl0, S[i][0]);
                S[i][1] = MFMA16(qh[i][kb], bh1, S[i][1]);
                S[i][1] = MFMA16(ql[i][kb], bh1, S[i][1]);
                S[i][1] = MFMA16(qh[i][kb], bl1, S[i][1]);
            }
        }

        // online softmax; O alpha-scale behind a wave-uniform vote
        float alph[2][4];
        int upd = 0;
#pragma unroll
        for (int i = 0; i < 2; ++i) {
#pragma unroll
            for (int k = 0; k < 4; ++k) {
                float s0 = av[i][k] * S[i][0][k] + bv[i][k] * y2v0;
                float s1 = av[i][k] * S[i][1][k] + bv[i][k] * y2v1;
                float rm = rowmax16(fmaxf(s0, s1));
                float mnew  = fmaxf(m_run[i][k], rm);
                float a_    = __expf(m_run[i][k] - mnew);   // ==1 when no update
                float p0 = __expf(s0 - mnew);
                float p1 = __expf(s1 - mnew);
                l_run[i][k] = l_run[i][k] * a_ + (p0 + p1);
                m_run[i][k] = mnew;
                alph[i][k]  = a_;
                upd |= (a_ < 1.0f);
                sP[wave][i][quad * 4 + k][l15]      = f2bf(p0);
                sP[wave][i][quad * 4 + k][16 + l15] = f2bf(p1);
            }
        }
        if (__any(upd)) {
#pragma unroll
            for (int i = 0; i < 2; ++i)
#pragma unroll
                for (int db = 0; db < 8; ++db)
#pragma unroll
                    for (int k = 0; k < 4; ++k) O[i][db][k] *= alph[i][k];
        }
        // same-wave sP write->read ordering (per-wave region, no barrier)
        asm volatile("s_waitcnt lgkmcnt(0)" ::: "memory");

        s16x8 pa0 = *(const s16x8*)&sP[wave][0][l15][quad * 8];
        s16x8 pa1 = *(const s16x8*)&sP[wave][1][l15][quad * 8];
#pragma unroll
        for (int db = 0; db < 8; ++db) {
            O[0][db] = MFMA16(pa0, vb[db], O[0][db]);
            O[1][db] = MFMA16(pa1, vb[db], O[1][db]);
        }

        // end-of-iter: drain next tile's staging, then barrier. This is the ONLY
        // barrier per iteration; its drain overlapped with the compute above.
        asm volatile("s_waitcnt vmcnt(0)" ::: "memory");
        __syncthreads();
    }

    // epilogue: unnormalized O + (m, l) partials
#pragma unroll
    for (int i = 0; i < 2; ++i) {
#pragma unroll
        for (int db = 0; db < 8; ++db) {
#pragma unroll
            for (int k = 0; k < 4; ++k) {
                int row = q0 + i * 16 + quad * 4 + k;
                partO[((size_t)chunk * N + row) * 128 + db * 16 + l15] = O[i][db][k];
            }
        }
#pragma unroll
        for (int k = 0; k < 4; ++k) {
            float lsum = rowsum16(l_run[i][k]);
            if (l15 == 0) {
                int row = q0 + i * 16 + quad * 4 + k;
                partML[((size_t)chunk * N + row) * 2 + 0] = m_run[i][k];
                partML[((size_t)chunk * N + row) * 2 + 1] = lsum;
            }
        }
    }
}

// ---------------------------------------------------------------- combine
__global__ void combine_kernel(const float* __restrict__ partO, const float* __restrict__ partML,
                               const float* __restrict__ x, const float* __restrict__ rowc,
                               float* __restrict__ out, int N, int split) {
    int n = blockIdx.x, d = threadIdx.x;
    float Mx = -INFINITY;
    for (int c = 0; c < split; ++c)
        Mx = fmaxf(Mx, partML[((size_t)c * N + n) * 2]);
    float L = 0.f, acc = 0.f;
    for (int c = 0; c < split; ++c) {
        float w = __expf(partML[((size_t)c * N + n) * 2] - Mx);
        L   += w * partML[((size_t)c * N + n) * 2 + 1];
        acc += w * partO[((size_t)c * N + n) * 128 + d];
    }
    float evals = acc / L;
    if (evals != evals) evals = 0.f;   // reference's isnan guard
    float iv = rowc[n * 4 + 2];
    out[(size_t)n * 128 + d] = (evals - x[(size_t)n * 128 + d]) * iv;
}

// ---------------------------------------------------------------- launch
extern "C" void kernel_launch(void* const* d_in, const int* in_sizes, int n_in,
                              void* d_out, int out_size, void* d_ws, size_t ws_size,
                              hipStream_t stream) {
    const float* x     = (const float*)d_in[0];
    const float* t     = (const float*)d_in[1];
    const float* train = (const float*)d_in[2];
    float* out = (float*)d_out;

    const int N = in_sizes[1];            // 4096
    const int D = 128;
    const int M = in_sizes[2] / D;        // 16384

    char* ws = (char*)d_ws;
    size_t off = 0;
    auto alloc = [&](size_t bytes) -> void* {
        void* p = ws + off;
        off = (off + bytes + 255) & ~(size_t)255;
        return p;
    };
    u16* Khi   = (u16*)alloc((size_t)M * D * 2);
    u16* Klo   = (u16*)alloc((size_t)M * D * 2);
    u16* Vt    = (u16*)alloc((size_t)M * D * 2);
    u16* Qhi   = (u16*)alloc((size_t)N * D * 2);
    u16* Qlo   = (u16*)alloc((size_t)N * D * 2);
    float* rowc = (float*)alloc((size_t)N * 16);
    float* y2   = (float*)alloc((size_t)M * 4);
    size_t base = off;
    size_t per  = (size_t)N * D * 4 + (size_t)N * 8 + 512;   // partO + partML per chunk
    int split = 16;                       // 512 blocks = 2/CU; combine traffic halved vs 32
    while (split > 1 && base + per * split > ws_size) split >>= 1;
    float* partO  = (float*)alloc((size_t)split * N * D * 4);
    float* partML = (float*)alloc((size_t)split * N * 8);

    prep_x_kernel<<<(N * 32 + 255) / 256, 256, 0, stream>>>(x, t, Qhi, Qlo, rowc, N);
    prep_train_kernel<<<M / 4, 256, 0, stream>>>(train, Khi, Klo, Vt, y2, M);

    int mchunk = M / split;
    dim3 grid(N / 128, split);
    flash_kernel<<<grid, 256, 0, stream>>>(Khi, Klo, Vt, Qhi, Qlo, rowc, y2,
                                           partO, partML, N, M, mchunk);
    combine_kernel<<<N, 128, 0, stream>>>(partO, partML, x, rowc, out, N, split);
}